// Round 2
// baseline (305.127 us; speedup 1.0000x reference)
//
#include <hip/hip_runtime.h>
#include <hip/hip_bf16.h>

// BranchTeacherLayoutLoss — fused gather+normalize+segment-sum, then per-segment epilogue.
// directions[i] = x*scale/max(||x*scale||,1e-8), scale = (||x||>1-eps) ? (1-eps)/max(||x||,1e-12) : 1
// segment_ids SORTED -> per-wave running accumulator, flush on boundary (rare: avg seg len ~390).
// Inner loop unrolled x4 (fast path when all 4 members share cur_seg) for 4x outstanding loads
// + 4 interleaved shuffle-reduction chains.

constexpr int D = 256;          // feature dim (fixed by reference)
constexpr int CHUNK = 32;       // members per wave
constexpr float MAXNORM = 1.0f - 1e-5f;

__device__ __forceinline__ float wave_reduce_add(float v) {
    #pragma unroll
    for (int off = 32; off >= 1; off >>= 1)
        v += __shfl_xor(v, off, 64);
    return v;
}

__global__ void __launch_bounds__(256)
gather_accum_kernel(const float* __restrict__ emb,
                    const int*   __restrict__ midx,
                    const int*   __restrict__ segid,
                    float* __restrict__ seg_sum,   // [B][D]
                    float* __restrict__ counts,    // [B]
                    int M) {
    const int wave = blockIdx.x * (blockDim.x >> 6) + (threadIdx.x >> 6);
    const int lane = threadIdx.x & 63;
    int m = wave * CHUNK;
    if (m >= M) return;
    const int mend = min(m + CHUNK, M);

    float4 acc = {0.f, 0.f, 0.f, 0.f};
    float  cnt = 0.f;
    int cur_seg = segid[m];

    while (m < mend) {
        if (m + 4 <= mend && segid[m + 3] == cur_seg) {
            // ---- fast path: 4 members, all in cur_seg (sorted ids) ----
            const int i0 = midx[m + 0], i1 = midx[m + 1], i2 = midx[m + 2], i3 = midx[m + 3];
            const float4 v0 = *reinterpret_cast<const float4*>(emb + (size_t)i0 * D + lane * 4);
            const float4 v1 = *reinterpret_cast<const float4*>(emb + (size_t)i1 * D + lane * 4);
            const float4 v2 = *reinterpret_cast<const float4*>(emb + (size_t)i2 * D + lane * 4);
            const float4 v3 = *reinterpret_cast<const float4*>(emb + (size_t)i3 * D + lane * 4);
            float s[4];
            s[0] = v0.x * v0.x + v0.y * v0.y + v0.z * v0.z + v0.w * v0.w;
            s[1] = v1.x * v1.x + v1.y * v1.y + v1.z * v1.z + v1.w * v1.w;
            s[2] = v2.x * v2.x + v2.y * v2.y + v2.z * v2.z + v2.w * v2.w;
            s[3] = v3.x * v3.x + v3.y * v3.y + v3.z * v3.z + v3.w * v3.w;
            #pragma unroll
            for (int off = 32; off >= 1; off >>= 1) {
                #pragma unroll
                for (int j = 0; j < 4; ++j)
                    s[j] += __shfl_xor(s[j], off, 64);   // 4 independent chains interleave
            }
            float f[4];
            #pragma unroll
            for (int j = 0; j < 4; ++j) {
                const float norm  = sqrtf(s[j]);
                const float scale = (norm > MAXNORM) ? (MAXNORM / fmaxf(norm, 1e-12f)) : 1.0f;
                f[j] = scale / fmaxf(norm * scale, 1e-8f);
            }
            acc.x += v0.x * f[0] + v1.x * f[1] + v2.x * f[2] + v3.x * f[3];
            acc.y += v0.y * f[0] + v1.y * f[1] + v2.y * f[2] + v3.y * f[3];
            acc.z += v0.z * f[0] + v1.z * f[1] + v2.z * f[2] + v3.z * f[3];
            acc.w += v0.w * f[0] + v1.w * f[1] + v2.w * f[2] + v3.w * f[3];
            cnt += 4.f;
            m += 4;
        } else {
            // ---- scalar path: boundary or tail ----
            const int seg = segid[m];
            if (seg != cur_seg) {
                float* dst = seg_sum + (size_t)cur_seg * D + lane * 4;
                atomicAdd(dst + 0, acc.x);
                atomicAdd(dst + 1, acc.y);
                atomicAdd(dst + 2, acc.z);
                atomicAdd(dst + 3, acc.w);
                if (lane == 0) atomicAdd(&counts[cur_seg], cnt);
                acc = {0.f, 0.f, 0.f, 0.f};
                cnt = 0.f;
                cur_seg = seg;
            }
            const int idx = midx[m];
            const float4 v = *reinterpret_cast<const float4*>(emb + (size_t)idx * D + lane * 4);
            float ss = v.x * v.x + v.y * v.y + v.z * v.z + v.w * v.w;
            ss = wave_reduce_add(ss);
            const float norm  = sqrtf(ss);
            const float scale = (norm > MAXNORM) ? (MAXNORM / fmaxf(norm, 1e-12f)) : 1.0f;
            const float f     = scale / fmaxf(norm * scale, 1e-8f);
            acc.x += v.x * f;
            acc.y += v.y * f;
            acc.z += v.z * f;
            acc.w += v.w * f;
            cnt += 1.f;
            m += 1;
        }
    }
    // final flush
    float* dst = seg_sum + (size_t)cur_seg * D + lane * 4;
    atomicAdd(dst + 0, acc.x);
    atomicAdd(dst + 1, acc.y);
    atomicAdd(dst + 2, acc.z);
    atomicAdd(dst + 3, acc.w);
    if (lane == 0) atomicAdd(&counts[cur_seg], cnt);
}

__global__ void __launch_bounds__(256)
finalize_kernel(const float* __restrict__ seg_sum,
                const float* __restrict__ counts,
                const float* __restrict__ tcent,
                const float* __restrict__ tcoh,
                float* __restrict__ out,
                int B) {
    const int seg  = blockIdx.x * (blockDim.x >> 6) + (threadIdx.x >> 6);
    const int lane = threadIdx.x & 63;
    if (seg >= B) return;

    const float4 s = *reinterpret_cast<const float4*>(seg_sum + (size_t)seg * D + lane * 4);
    const float  c = fmaxf(counts[seg], 1.0f);
    const float inv_c = 1.0f / c;
    float4 mean = {s.x * inv_c, s.y * inv_c, s.z * inv_c, s.w * inv_c};

    float ss = mean.x * mean.x + mean.y * mean.y + mean.z * mean.z + mean.w * mean.w;
    ss = wave_reduce_add(ss);                         // ||mean_raw||^2
    const float mnorm = sqrtf(ss);
    const float inv   = 1.0f / fmaxf(mnorm, 1e-12f);  // centroid = mean * inv

    const float4 t = *reinterpret_cast<const float4*>(tcent + (size_t)seg * D + lane * 4);
    float dt = mean.x * t.x + mean.y * t.y + mean.z * t.z + mean.w * t.w;
    dt = wave_reduce_add(dt) * inv;                   // <centroid, teacher>

    const float centroid_loss = 1.0f - dt;
    const float cohesion      = 1.0f - ss * inv;      // 1 - <mean_raw, centroid> = 1 - ||mean||
    const float coh_loss      = fmaxf(cohesion - tcoh[seg], 0.0f);

    if (lane == 0)
        atomicAdd(out, (centroid_loss + coh_loss) / (float)B);
}

extern "C" void kernel_launch(void* const* d_in, const int* in_sizes, int n_in,
                              void* d_out, int out_size, void* d_ws, size_t ws_size,
                              hipStream_t stream) {
    const float* emb   = (const float*)d_in[0];   // [N, 256]
    const float* tcent = (const float*)d_in[1];   // [B, 256]
    const float* tcoh  = (const float*)d_in[2];   // [B]
    const int*   midx  = (const int*)d_in[3];     // [M]
    const int*   segid = (const int*)d_in[4];     // [M]
    const int B = in_sizes[2];
    const int M = in_sizes[3];

    float* seg_sum = (float*)d_ws;                // B*D floats
    float* counts  = seg_sum + (size_t)B * D;     // B floats

    hipMemsetAsync(d_ws, 0, ((size_t)B * D + B) * sizeof(float), stream);
    hipMemsetAsync(d_out, 0, sizeof(float), stream);

    const int waves_per_block = 4;                // 256 threads = 4 waves
    const int n_waves = (M + CHUNK - 1) / CHUNK;
    const int blocks  = (n_waves + waves_per_block - 1) / waves_per_block;
    gather_accum_kernel<<<blocks, 256, 0, stream>>>(emb, midx, segid, seg_sum, counts, M);

    const int blocks2 = (B + waves_per_block - 1) / waves_per_block;
    finalize_kernel<<<blocks2, 256, 0, stream>>>(seg_sum, counts, tcent, tcoh, (float*)d_out, B);
}